// Round 4
// baseline (577.724 us; speedup 1.0000x reference)
//
#include <hip/hip_runtime.h>
#include <hip/hip_bf16.h>
#include <stdint.h>

// Problem constants (match setup_inputs)
#define M_ROWS 100352   // 2048 * 49
#define C_DIM  512
#define QKV_N  1536
#define NH     16
#define HD     32
#define NWIN   49       // window tokens (7*7)
#define NMASK  64

typedef __attribute__((ext_vector_type(4))) float        f32x4;
typedef __attribute__((ext_vector_type(8))) short        bf16x8;
typedef __attribute__((ext_vector_type(4))) unsigned int u32x4;

static __device__ __forceinline__ unsigned short f32_to_bf16(float f) {
  union { float f; unsigned int u; } v; v.f = f;
  unsigned int u = v.u;
  return (unsigned short)((u + 0x7FFFu + ((u >> 16) & 1u)) >> 16);  // RNE
}

// global -> LDS direct DMA, 16B per lane. dest = wave-uniform base + lane*16.
static __device__ __forceinline__ void gload_lds16(const void* g, void* l) {
  __builtin_amdgcn_global_load_lds(
      (const __attribute__((address_space(1))) unsigned int*)g,
      (__attribute__((address_space(3))) unsigned int*)l, 16, 0, 0);
}

// ---------------------------------------------------------------- k_cvt
__global__ void k_cvt(const float* __restrict__ in, unsigned short* __restrict__ out, int n4) {
  int i = blockIdx.x * blockDim.x + threadIdx.x;
  int stride = gridDim.x * blockDim.x;
  for (; i < n4; i += stride) {
    float4 v = ((const float4*)in)[i];
    ushort4 o = make_ushort4(f32_to_bf16(v.x), f32_to_bf16(v.y),
                             f32_to_bf16(v.z), f32_to_bf16(v.w));
    ((ushort4*)out)[i] = o;
  }
}

// ------------------------------------------- transpose + convert weights
// in: K x N f32 (row-major), out: N x K bf16 (row-major) == B^T
__global__ void k_transpose_cvt(const float* __restrict__ in, unsigned short* __restrict__ out,
                                int K, int N) {
  __shared__ float t[32][33];
  const int n0 = blockIdx.x * 32, k0 = blockIdx.y * 32;
  const int tx = threadIdx.x & 31, ty = threadIdx.x >> 5;  // 32 x 8
#pragma unroll
  for (int rr = 0; rr < 32; rr += 8)
    t[ty + rr][tx] = in[(size_t)(k0 + ty + rr) * N + n0 + tx];
  __syncthreads();
#pragma unroll
  for (int rr = 0; rr < 32; rr += 8)
    out[(size_t)(n0 + ty + rr) * K + k0 + tx] = f32_to_bf16(t[tx][ty + rr]);
}

// ----------------------------------------- fused bias+mask table (padded)
// bmt[w][h][i][j] (64x16x64x64 f32) = mask[w][i][j] + bias[h][i][j], -1e30 pad.
__global__ __launch_bounds__(256) void k_bm(const float* __restrict__ mask,
                                            const float* __restrict__ rel,
                                            float* __restrict__ bmt) {
  const int idx = blockIdx.x * 256 + threadIdx.x;   // w<<16 | h<<12 | i<<6 | j
  const int j = idx & 63, i = (idx >> 6) & 63, h = (idx >> 12) & 15, w = idx >> 16;
  float v = -1e30f;
  if (i < NWIN && j < NWIN) {
    const int rpi = ((j / 7) - (i / 7) + 6) * 13;
    v = mask[w * (NWIN * NWIN) + i * NWIN + j] + rel[rpi * NH + h];
  }
  bmt[idx] = v;
}

// ------------------------------------------------------------------ GEMM
// C[M,N] = A[M,K](bf16) * BT[N,K]^T(bf16) + bias[N].
// 256x256 tile, BK=64, 512 threads = 8 waves (2Mx4N), 128 KB LDS dbuf.
//
// LDS: per op, per K-tile: 2 halves (128 rows) x 16 subtiles.  Subtile holds
// 16 rows x 32 cols stored TRANSPOSED-by-colgroup: [cg 0..3][row 0..15][8 col]
// (1024 B).  Frag read byte = cg*256 + row*16 -> 16B granule = row&7: every
// 8 consecutive lanes hit 8 distinct granules; 2 lanes/granule wave-wide
// (free, m136).  gload_lds dest stays LINEAR (lane*16); the permutation is
// carried by the per-lane GLOBAL source address (HK s09 pattern).
//
// Pipeline (T3/T4): stage(t+1) issued at top of iter t; s_waitcnt vmcnt(8)
// (drains tile-t loads only, keeps t+1's 8 in flight across both barriers —
// never vmcnt(0) in main loop); raw s_barrier pair; setprio(1) around MFMA.
// Race audit: stage(t+1) writes buf last read in iter t-1, guarded by iter
// t-1's end barrier; tile-t data landed = own vmcnt(8) (FIFO oldest) + pre-
// compute barrier publishing all waves' stages.
template <int OUT_BF16>
__global__ __launch_bounds__(512, 2) void k_gemm256(const unsigned short* __restrict__ A,
                                                    const unsigned short* __restrict__ BT,
                                                    const float* __restrict__ bias,
                                                    void* __restrict__ Cout,
                                                    int M, int N, int K) {
  __shared__ __align__(16) unsigned short lds[2][2][16384];  // [buf][A|B][2 half x 16 sub x 512]
  const int tid = threadIdx.x;
  const int lane = tid & 63, wave = tid >> 6;
  const int wr = wave >> 2, wc = wave & 3;      // 2 x 4 wave grid
  const int lr = lane & 15, lg = lane >> 4;

  // bijective XCD swizzle (gridDim.x % 8 == 0 for all call sites)
  const int nwg = gridDim.x, q8 = nwg >> 3;
  const int wg = (blockIdx.x & 7) * q8 + (blockIdx.x >> 3);
  const int gx = N >> 8;
  const int bx = wg % gx, by = wg / gx;
  const int m0 = by << 8, n0 = bx << 8;

  // staging source coords for this lane (chunk c = lane: cg=lane>>4, row=lane&15)
  const int srow = lane & 15;
  const int scol = (lane >> 4) * 8;

  const f32x4 fz = {0.f, 0.f, 0.f, 0.f};
  f32x4 acc[8][4];
#pragma unroll
  for (int i = 0; i < 8; ++i)
#pragma unroll
    for (int j = 0; j < 4; ++j) acc[i][j] = fz;

  const int NT = K >> 6;

  auto stage = [&](int t, int buf) {
    const int k0 = t << 6;
#pragma unroll
    for (int i = 0; i < 2; ++i) {
      const int s = wave + i * 8;          // subtile within half (0..15)
      const int rg = s >> 1, cg32 = s & 1;
      const size_t gc = (size_t)(k0 + cg32 * 32 + scol);
#pragma unroll
      for (int h = 0; h < 2; ++h) {
        gload_lds16(A + (size_t)(m0 + h * 128 + rg * 16 + srow) * K + gc,
                    &lds[buf][0][h * 8192 + s * 512]);
        gload_lds16(BT + (size_t)(n0 + h * 128 + rg * 16 + srow) * K + gc,
                    &lds[buf][1][h * 8192 + s * 512]);
      }
    }
  };

  const int roff = lg * 128 + lr * 8;   // ushort offset within subtile

  stage(0, 0);
  for (int t = 0; t < NT; ++t) {
    const int cur = t & 1;
    if (t + 1 < NT) {
      stage(t + 1, cur ^ 1);
      asm volatile("s_waitcnt vmcnt(8)" ::: "memory");   // drain tile t only
    } else {
      asm volatile("s_waitcnt vmcnt(0)" ::: "memory");
    }
    __builtin_amdgcn_sched_barrier(0);
    __builtin_amdgcn_s_barrier();       // all waves' tile-t stages published
    __builtin_amdgcn_sched_barrier(0);

    const unsigned short* la = &lds[cur][0][wr * 8192];
    const unsigned short* lb = &lds[cur][1][(wc >> 1) * 8192];
    bf16x8 bfr[4][2];
#pragma unroll
    for (int nj = 0; nj < 4; ++nj)
#pragma unroll
      for (int ks = 0; ks < 2; ++ks)
        bfr[nj][ks] = *(const bf16x8*)(lb + (((wc & 1) * 4 + nj) * 2 + ks) * 512 + roff);
#pragma unroll
    for (int mi = 0; mi < 8; ++mi) {
      bf16x8 af0 = *(const bf16x8*)(la + (mi * 2 + 0) * 512 + roff);
      bf16x8 af1 = *(const bf16x8*)(la + (mi * 2 + 1) * 512 + roff);
      __builtin_amdgcn_s_setprio(1);
#pragma unroll
      for (int nj = 0; nj < 4; ++nj) {
        acc[mi][nj] = __builtin_amdgcn_mfma_f32_16x16x32_bf16(af0, bfr[nj][0], acc[mi][nj], 0, 0, 0);
        acc[mi][nj] = __builtin_amdgcn_mfma_f32_16x16x32_bf16(af1, bfr[nj][1], acc[mi][nj], 0, 0, 0);
      }
      __builtin_amdgcn_s_setprio(0);
    }
    __builtin_amdgcn_s_barrier();       // readers done before next stage overwrites
    __builtin_amdgcn_sched_barrier(0);
  }

  float bv[4];
#pragma unroll
  for (int nj = 0; nj < 4; ++nj) bv[nj] = bias[n0 + wc * 64 + nj * 16 + lr];
#pragma unroll
  for (int mi = 0; mi < 8; ++mi)
#pragma unroll
    for (int nj = 0; nj < 4; ++nj)
#pragma unroll
      for (int r = 0; r < 4; ++r) {
        const int row = m0 + wr * 128 + mi * 16 + 4 * lg + r;
        const int col = n0 + wc * 64 + nj * 16 + lr;
        const float v = acc[mi][nj][r] + bv[nj];
        if (OUT_BF16)
          ((unsigned short*)Cout)[(size_t)row * N + col] = f32_to_bf16(v);
        else
          ((float*)Cout)[(size_t)row * N + col] = v;
      }
}

// ------------------------------------------------------------- attention
// 4 waves/block, one (b,h) per wave, zero barriers (waves independent).
__global__ __launch_bounds__(256) void k_attn(const unsigned short* __restrict__ qkv,
                                              const float* __restrict__ bmt,
                                              unsigned short* __restrict__ aout) {
  const int wave = threadIdx.x >> 6, lane = threadIdx.x & 63;
  const int lr = lane & 15, lg = lane >> 4;
  const int idx = blockIdx.x * 4 + wave;
  const int b = idx >> 4, h = idx & 15, w = b & 63;

  __shared__ __align__(16) unsigned short Pl[4][2048];  // [32 rows][64] swizzled
  __shared__ __align__(16) unsigned short Vt[4][2112];  // V^T, stride 66
  unsigned short* pl = Pl[wave];
  unsigned short* vt = Vt[wave];

  const unsigned short* qp = qkv + (size_t)b * NWIN * QKV_N + h * HD;
  const unsigned short* kp = qp + C_DIM;
  const unsigned short* vp = qp + 2 * C_DIM;

  bf16x8 kf[4], qf[4];
#pragma unroll
  for (int t = 0; t < 4; ++t) {
    kf[t] = *(const bf16x8*)(kp + (size_t)(t * 16 + lr) * QKV_N + lg * 8);
    qf[t] = *(const bf16x8*)(qp + (size_t)(t * 16 + lr) * QKV_N + lg * 8);
  }

  const u32x4 zv = {0u, 0u, 0u, 0u};
#pragma unroll
  for (int c0 = 0; c0 < 4; ++c0) {
    const int c = c0 * 64 + lane;
    const int key = c >> 2, d0 = (c & 3) << 3;
    union { u32x4 v; unsigned short s[8]; } tmp;
    tmp.v = (key < NWIN) ? *(const u32x4*)(vp + (size_t)key * QKV_N + d0) : zv;
#pragma unroll
    for (int jj = 0; jj < 8; ++jj) vt[(d0 + jj) * 66 + key] = tmp.s[jj];
  }

  const f32x4 fz = {0.f, 0.f, 0.f, 0.f};
  f32x4 s[4][4];  // [mi = j-frag][ni = i-frag]
#pragma unroll
  for (int mi = 0; mi < 4; ++mi)
#pragma unroll
    for (int ni = 0; ni < 4; ++ni) s[mi][ni] = fz;
#pragma unroll
  for (int mi = 0; mi < 4; ++mi)
#pragma unroll
    for (int ni = 0; ni < 4; ++ni)
      s[mi][ni] = __builtin_amdgcn_mfma_f32_16x16x32_bf16(kf[mi], qf[ni], s[mi][ni], 0, 0, 0);

  union VU { unsigned int u[4]; bf16x8 v; };
  VU vfr[2][2];  // [nj][ks]
#pragma unroll
  for (int nj = 0; nj < 2; ++nj)
#pragma unroll
    for (int ks = 0; ks < 2; ++ks) {
      const int base = ((16 * nj + lr) * 66 + 32 * ks + 8 * lg) >> 1;
#pragma unroll
      for (int u = 0; u < 4; ++u) vfr[nj][ks].u[u] = ((const unsigned int*)vt)[base + u];
    }

  const float scale = 0.1767766952966369f;  // 32^-0.5
  const float* tbl = bmt + ((size_t)(w * NH + h) << 12);

  f32x4 o[4][2];
#pragma unroll
  for (int qi = 0; qi < 4; ++qi)
#pragma unroll
    for (int nj = 0; nj < 2; ++nj) o[qi][nj] = fz;

#pragma unroll
  for (int ni = 0; ni < 4; ++ni) {
    float v[16];
    float mx = -3e38f;
#pragma unroll
    for (int mi = 0; mi < 4; ++mi) {
      const f32x4 t4 = *(const f32x4*)(tbl + (16 * ni + lr) * 64 + 16 * mi + 4 * lg);
#pragma unroll
      for (int r = 0; r < 4; ++r) {
        v[mi * 4 + r] = fmaf(s[mi][ni][r], scale, t4[r]);
        mx = fmaxf(mx, v[mi * 4 + r]);
      }
    }
    mx = fmaxf(mx, __shfl_xor(mx, 16));
    mx = fmaxf(mx, __shfl_xor(mx, 32));
    float sum = 0.f;
#pragma unroll
    for (int t = 0; t < 16; ++t) {
      v[t] = __expf(v[t] - mx);
      sum += v[t];
    }
    sum += __shfl_xor(sum, 16);
    sum += __shfl_xor(sum, 32);
    const float inv = __builtin_amdgcn_rcpf(sum);

    const int ip = 16 * (ni & 1) + lr;
#pragma unroll
    for (int mi = 0; mi < 4; ++mi) {
      const unsigned int lo = (unsigned int)f32_to_bf16(v[mi * 4 + 0] * inv) |
                              ((unsigned int)f32_to_bf16(v[mi * 4 + 1] * inv) << 16);
      const unsigned int hi = (unsigned int)f32_to_bf16(v[mi * 4 + 2] * inv) |
                              ((unsigned int)f32_to_bf16(v[mi * 4 + 3] * inv) << 16);
      const int byteoff = 32 * mi + 8 * lg;
      const int sw = byteoff ^ ((ip & 7) << 4);
      uint2 w2; w2.x = lo; w2.y = hi;
      *(uint2*)((char*)pl + ip * 128 + sw) = w2;
    }

    if (ni & 1) {
      asm volatile("s_waitcnt lgkmcnt(0)" ::: "memory");
      __builtin_amdgcn_sched_barrier(0);
      const int half = ni >> 1;
#pragma unroll
      for (int q2 = 0; q2 < 2; ++q2) {
        const int qi = half * 2 + q2;
        const int ipr = 16 * q2 + lr;
#pragma unroll
        for (int ks = 0; ks < 2; ++ks) {
          const int bo = 64 * ks + 16 * lg;
          const int swr = bo ^ ((ipr & 7) << 4);
          const bf16x8 pa = *(const bf16x8*)((const char*)pl + ipr * 128 + swr);
#pragma unroll
          for (int nj = 0; nj < 2; ++nj)
            o[qi][nj] = __builtin_amdgcn_mfma_f32_16x16x32_bf16(pa, vfr[nj][ks].v, o[qi][nj], 0, 0, 0);
        }
      }
    }
  }

  const size_t orow = (size_t)b * NWIN;
#pragma unroll
  for (int qi = 0; qi < 4; ++qi)
#pragma unroll
    for (int r = 0; r < 4; ++r) {
      const int i = 16 * qi + 4 * lg + r;
      if (i < NWIN) {
#pragma unroll
        for (int nj = 0; nj < 2; ++nj)
          aout[(orow + i) * C_DIM + h * HD + 16 * nj + lr] = f32_to_bf16(o[qi][nj][r]);
      }
    }
}

// ---------------------------------------------------------------- launch
static const size_t SZ_QKV = (size_t)M_ROWS * QKV_N * 2;
static const size_t SZ_XB  = (size_t)M_ROWS * C_DIM * 2;
static const size_t SZ_WQ  = (size_t)QKV_N * C_DIM * 2;
static const size_t OFF_QKV = 0;
static const size_t OFF_XB  = OFF_QKV + SZ_QKV;   // x_bf16, later reused as attn_out
static const size_t OFF_WQ  = OFF_XB + SZ_XB;
static const size_t OFF_WP  = OFF_WQ + SZ_WQ;

extern "C" void kernel_launch(void* const* d_in, const int* in_sizes, int n_in,
                              void* d_out, int out_size, void* d_ws, size_t ws_size,
                              hipStream_t stream) {
  const float* x      = (const float*)d_in[0];
  const float* mask   = (const float*)d_in[1];
  const float* qkv_w  = (const float*)d_in[2];
  const float* qkv_b  = (const float*)d_in[3];
  const float* proj_w = (const float*)d_in[4];
  const float* proj_b = (const float*)d_in[5];
  const float* rel    = (const float*)d_in[6];
  float* out = (float*)d_out;

  char* ws = (char*)d_ws;
  unsigned short* qkvb = (unsigned short*)(ws + OFF_QKV);
  unsigned short* xb   = (unsigned short*)(ws + OFF_XB);
  unsigned short* wqT  = (unsigned short*)(ws + OFF_WQ);
  unsigned short* wpT  = (unsigned short*)(ws + OFF_WP);
  // bmt (16.78 MB) in d_out scratch: fully consumed by k_attn before final GEMM.
  float* bmt = (float*)d_out;

  k_cvt<<<2048, 256, 0, stream>>>(x, xb, M_ROWS * C_DIM / 4);
  k_transpose_cvt<<<dim3(QKV_N / 32, C_DIM / 32), 256, 0, stream>>>(qkv_w, wqT, C_DIM, QKV_N);
  k_transpose_cvt<<<dim3(C_DIM / 32, C_DIM / 32), 256, 0, stream>>>(proj_w, wpT, C_DIM, C_DIM);
  k_bm<<<(NMASK * NH * 64 * 64) / 256, 256, 0, stream>>>(mask, rel, bmt);

  // qkv = x @ qkv_w + qkv_b   (bf16 out), grid 6*392 = 2352 (%8==0)
  k_gemm256<1><<<(QKV_N / 256) * (M_ROWS / 256), 512, 0, stream>>>(
      xb, wqT, qkv_b, qkvb, M_ROWS, QKV_N, C_DIM);

  // attention -> attn_out (reuses xb region)
  k_attn<<<2048 * NH / 4, 256, 0, stream>>>(qkvb, bmt, xb);

  // out = attn_out @ proj_w + proj_b  (f32 out), grid 2*392 = 784 (%8==0)
  k_gemm256<0><<<(C_DIM / 256) * (M_ROWS / 256), 512, 0, stream>>>(
      xb, wpT, proj_b, out, M_ROWS, C_DIM, C_DIM);
}

// Round 5
// 539.450 us; speedup vs baseline: 1.0709x; 1.0709x over previous
//
#include <hip/hip_runtime.h>
#include <hip/hip_bf16.h>
#include <stdint.h>

// Problem constants (match setup_inputs)
#define M_ROWS 100352   // 2048 * 49
#define C_DIM  512
#define QKV_N  1536
#define NH     16
#define HD     32
#define NWIN   49       // window tokens (7*7)
#define NMASK  64

typedef __attribute__((ext_vector_type(4))) float        f32x4;
typedef __attribute__((ext_vector_type(8))) short        bf16x8;
typedef __attribute__((ext_vector_type(4))) unsigned int u32x4;

static __device__ __forceinline__ unsigned short f32_to_bf16(float f) {
  union { float f; unsigned int u; } v; v.f = f;
  unsigned int u = v.u;
  return (unsigned short)((u + 0x7FFFu + ((u >> 16) & 1u)) >> 16);  // RNE
}

// global -> LDS direct DMA, 16B per lane. dest = wave-uniform base + lane*16.
static __device__ __forceinline__ void gload_lds16(const void* g, void* l) {
  __builtin_amdgcn_global_load_lds(
      (const __attribute__((address_space(1))) unsigned int*)g,
      (__attribute__((address_space(3))) unsigned int*)l, 16, 0, 0);
}

// ---------------------------------------------------------------- k_cvt
__global__ void k_cvt(const float* __restrict__ in, unsigned short* __restrict__ out, int n4) {
  int i = blockIdx.x * blockDim.x + threadIdx.x;
  int stride = gridDim.x * blockDim.x;
  for (; i < n4; i += stride) {
    float4 v = ((const float4*)in)[i];
    ushort4 o = make_ushort4(f32_to_bf16(v.x), f32_to_bf16(v.y),
                             f32_to_bf16(v.z), f32_to_bf16(v.w));
    ((ushort4*)out)[i] = o;
  }
}

// ------------------------------------------- transpose + convert weights
// in: K x N f32 (row-major), out: N x K bf16 (row-major) == B^T
__global__ void k_transpose_cvt(const float* __restrict__ in, unsigned short* __restrict__ out,
                                int K, int N) {
  __shared__ float t[32][33];
  const int n0 = blockIdx.x * 32, k0 = blockIdx.y * 32;
  const int tx = threadIdx.x & 31, ty = threadIdx.x >> 5;  // 32 x 8
#pragma unroll
  for (int rr = 0; rr < 32; rr += 8)
    t[ty + rr][tx] = in[(size_t)(k0 + ty + rr) * N + n0 + tx];
  __syncthreads();
#pragma unroll
  for (int rr = 0; rr < 32; rr += 8)
    out[(size_t)(n0 + ty + rr) * K + k0 + tx] = f32_to_bf16(t[tx][ty + rr]);
}

// ----------------------------------------- fused bias+mask table (padded)
// bmt[w][h][i][j] (64x16x64x64 f32) = mask[w][i][j] + bias[h][i][j], -1e30 pad.
__global__ __launch_bounds__(256) void k_bm(const float* __restrict__ mask,
                                            const float* __restrict__ rel,
                                            float* __restrict__ bmt) {
  const int idx = blockIdx.x * 256 + threadIdx.x;   // w<<16 | h<<12 | i<<6 | j
  const int j = idx & 63, i = (idx >> 6) & 63, h = (idx >> 12) & 15, w = idx >> 16;
  float v = -1e30f;
  if (i < NWIN && j < NWIN) {
    const int rpi = ((j / 7) - (i / 7) + 6) * 13;
    v = mask[w * (NWIN * NWIN) + i * NWIN + j] + rel[rpi * NH + h];
  }
  bmt[idx] = v;
}

// ------------------------------------------------------------------ GEMM
// C[M,N] = A[M,K](bf16) * BT[N,K]^T(bf16) + bias[N].
// 256x256 tile, BK=64, 512 threads = 8 waves (2Mx4N), 128 KB LDS dbuf.
//
// LDS: [buf][op][2 half x 16 subtile x 512].  Subtile = 16 rows x 32 cols
// stored [cg 0..3][row 0..15][8 col] (1 KB) -> conflict-free ds_read_b128
// (verified: 0 SQ_LDS_BANK_CONFLICT in r4).  gload_lds dest LINEAR; the
// permutation carried by the per-lane GLOBAL source address.
//
// 8-phase pipeline (T3+T4+T5): K-tile h = 4 quadrant phases (mh,nh) =
// (0,0),(0,1),(1,1),(1,0).  Each phase: stage 2x8KB units of tile h+1
// (unit order per tile: B0,B1 | B2,B3 | A0,A2 | A1,A3 - B first since every
// wave reads its B unit at q0; A1/A3 not needed until q2) || ds_read this
// quadrant's frags || 16 MFMA under setprio(1).  Counted waits, never 0 in
// main loop: q0 vmcnt(2) (drains B-all + A0,A2 of current tile, keeps the
// A1,A3 stage pair), q2 vmcnt(4) (drains A1,A3, keeps q0/q1 stage pairs).
// Prologue stages tile 0 in the same unit order -> iteration 0 is uniform.
// Last tile peeled: no stages, q2 uses vmcnt(0).  Barriers at q0/q2 only
// (publication); WAR across tiles guarded by q0 barrier (each wave passes
// it only after its own q3 reads; stages always target buf (h+1)&1 while
// reads hit buf h&1).
#define WAITB(N)                                              \
  do {                                                        \
    asm volatile("s_waitcnt vmcnt(" #N ")" ::: "memory");     \
    __builtin_amdgcn_sched_barrier(0);                        \
    __builtin_amdgcn_s_barrier();                             \
    __builtin_amdgcn_sched_barrier(0);                        \
  } while (0)

template <int OUT_BF16>
__global__ __launch_bounds__(512, 2) void k_gemm256(const unsigned short* __restrict__ A,
                                                    const unsigned short* __restrict__ BT,
                                                    const float* __restrict__ bias,
                                                    void* __restrict__ Cout,
                                                    int M, int N, int K) {
  __shared__ __align__(16) unsigned short lds[2][2][16384];  // [buf][A|B] 128 KB
  const int tid = threadIdx.x;
  const int lane = tid & 63, wave = tid >> 6;
  const int wr = wave >> 2, wc = wave & 3;      // 2 x 4 wave grid
  const int lr = lane & 15, lg = lane >> 4;

  // bijective XCD swizzle (gridDim.x % 8 == 0 for all call sites)
  const int nwg = gridDim.x, q8 = nwg >> 3;
  const int wg = (blockIdx.x & 7) * q8 + (blockIdx.x >> 3);
  const int gx = N >> 8;
  const int bx = wg % gx, by = wg / gx;
  const int m0 = by << 8, n0 = bx << 8;

  // staging coords: wave w stages subtile (RG = 4u + (w>>1), cg = w&1) of
  // each unit u; lane -> row lane&15, colgroup (lane>>4)*8 of global src.
  const int srow = lane & 15;
  const int scol = (lane >> 4) * 8;
  const int sRG = wave >> 1;
  const int scg = wave & 1;

  const f32x4 fz = {0.f, 0.f, 0.f, 0.f};
  f32x4 acc[8][4];
#pragma unroll
  for (int i = 0; i < 8; ++i)
#pragma unroll
    for (int j = 0; j < 4; ++j) acc[i][j] = fz;

  const int NT = K >> 6;

  // stage one 8KB unit (1 load/lane): operand op (0=A base m0, 1=B base n0),
  // tile t, 64-row unit u (rows [64u, 64u+64) of the 256-row tile operand).
  auto stageU = [&](const unsigned short* G, int gbase, int op, int t, int u) {
    const int RG = 4 * u + sRG;  // row-group 0..15
    gload_lds16(G + (size_t)(gbase + RG * 16 + srow) * K + (t << 6) + scg * 32 + scol,
                &lds[t & 1][op][(RG >> 3) * 8192 + (((RG & 7) << 1) + scg) * 512]);
  };

  const int roff = lg * 128 + lr * 8;   // ushort offset within subtile

  bf16x8 af[4][2];   // current A half-frags
  bf16x8 bf[2][2];   // current B quadrant frags
  bf16x8 bg[2][2];   // second B quadrant frags

#define LDA(h, mh)                                                              \
  do {                                                                          \
    const unsigned short* la = &lds[(h) & 1][0][wr * 8192];                     \
    _Pragma("unroll") for (int m = 0; m < 4; ++m)                               \
    _Pragma("unroll") for (int ks = 0; ks < 2; ++ks)                            \
        af[m][ks] = *(const bf16x8*)(la + ((((mh)*4 + m) * 2 + ks) * 512) + roff); \
  } while (0)

#define LDB(h, nh, DST)                                                         \
  do {                                                                          \
    const unsigned short* lb = &lds[(h) & 1][1][(wc >> 1) * 8192];              \
    _Pragma("unroll") for (int n = 0; n < 2; ++n)                               \
    _Pragma("unroll") for (int ks = 0; ks < 2; ++ks)                            \
        DST[n][ks] = *(const bf16x8*)(lb + ((((wc & 1) * 4 + (nh)*2 + n) * 2 + ks) * 512) + roff); \
  } while (0)

#define MFMA16(mh, nh, B)                                                       \
  do {                                                                          \
    __builtin_amdgcn_s_setprio(1);                                              \
    _Pragma("unroll") for (int m = 0; m < 4; ++m)                               \
    _Pragma("unroll") for (int n = 0; n < 2; ++n)                               \
    _Pragma("unroll") for (int ks = 0; ks < 2; ++ks)                            \
        acc[(mh)*4 + m][(nh)*2 + n] = __builtin_amdgcn_mfma_f32_16x16x32_bf16(  \
            af[m][ks], B[n][ks], acc[(mh)*4 + m][(nh)*2 + n], 0, 0, 0);         \
    __builtin_amdgcn_s_setprio(0);                                              \
  } while (0)

  // prologue: tile 0, unit order B0 B1 B2 B3 A0 A2 A1 A3 (8 loads/lane)
  stageU(BT, n0, 1, 0, 0); stageU(BT, n0, 1, 0, 1);
  stageU(BT, n0, 1, 0, 2); stageU(BT, n0, 1, 0, 3);
  stageU(A,  m0, 0, 0, 0); stageU(A,  m0, 0, 0, 2);
  stageU(A,  m0, 0, 0, 1); stageU(A,  m0, 0, 0, 3);

  for (int h = 0; h < NT - 1; ++h) {
    const int t1 = h + 1;
    // q0: quadrant (0,0)
    WAITB(2);
    stageU(BT, n0, 1, t1, 0); stageU(BT, n0, 1, t1, 1);
    LDA(h, 0);
    LDB(h, 0, bf);
    MFMA16(0, 0, bf);
    // q1: quadrant (0,1)
    stageU(BT, n0, 1, t1, 2); stageU(BT, n0, 1, t1, 3);
    LDB(h, 1, bg);
    MFMA16(0, 1, bg);
    // q2: quadrant (1,1)
    WAITB(4);
    stageU(A, m0, 0, t1, 0); stageU(A, m0, 0, t1, 2);
    LDA(h, 1);
    MFMA16(1, 1, bg);
    // q3: quadrant (1,0)
    stageU(A, m0, 0, t1, 1); stageU(A, m0, 0, t1, 3);
    LDB(h, 0, bf);
    MFMA16(1, 0, bf);
  }
  {  // last tile, peeled: no stages; q2 drains fully
    const int h = NT - 1;
    WAITB(2);
    LDA(h, 0);
    LDB(h, 0, bf);
    MFMA16(0, 0, bf);
    LDB(h, 1, bg);
    MFMA16(0, 1, bg);
    WAITB(0);
    LDA(h, 1);
    MFMA16(1, 1, bg);
    LDB(h, 0, bf);
    MFMA16(1, 0, bf);
  }
#undef LDA
#undef LDB
#undef MFMA16

  float bv[4];
#pragma unroll
  for (int nj = 0; nj < 4; ++nj) bv[nj] = bias[n0 + wc * 64 + nj * 16 + lr];
#pragma unroll
  for (int mi = 0; mi < 8; ++mi)
#pragma unroll
    for (int nj = 0; nj < 4; ++nj)
#pragma unroll
      for (int r = 0; r < 4; ++r) {
        const int row = m0 + wr * 128 + mi * 16 + 4 * lg + r;
        const int col = n0 + wc * 64 + nj * 16 + lr;
        const float v = acc[mi][nj][r] + bv[nj];
        if (OUT_BF16)
          ((unsigned short*)Cout)[(size_t)row * N + col] = f32_to_bf16(v);
        else
          ((float*)Cout)[(size_t)row * N + col] = v;
      }
}

// ------------------------------------------------------------- attention
// 4 waves/block, one (b,h) per wave, zero barriers (waves independent).
__global__ __launch_bounds__(256) void k_attn(const unsigned short* __restrict__ qkv,
                                              const float* __restrict__ bmt,
                                              unsigned short* __restrict__ aout) {
  const int wave = threadIdx.x >> 6, lane = threadIdx.x & 63;
  const int lr = lane & 15, lg = lane >> 4;
  const int idx = blockIdx.x * 4 + wave;
  const int b = idx >> 4, h = idx & 15, w = b & 63;

  __shared__ __align__(16) unsigned short Pl[4][2048];  // [32 rows][64] swizzled
  __shared__ __align__(16) unsigned short Vt[4][2112];  // V^T, stride 66
  unsigned short* pl = Pl[wave];
  unsigned short* vt = Vt[wave];

  const unsigned short* qp = qkv + (size_t)b * NWIN * QKV_N + h * HD;
  const unsigned short* kp = qp + C_DIM;
  const unsigned short* vp = qp + 2 * C_DIM;

  bf16x8 kf[4], qf[4];
#pragma unroll
  for (int t = 0; t < 4; ++t) {
    kf[t] = *(const bf16x8*)(kp + (size_t)(t * 16 + lr) * QKV_N + lg * 8);
    qf[t] = *(const bf16x8*)(qp + (size_t)(t * 16 + lr) * QKV_N + lg * 8);
  }

  const u32x4 zv = {0u, 0u, 0u, 0u};
#pragma unroll
  for (int c0 = 0; c0 < 4; ++c0) {
    const int c = c0 * 64 + lane;
    const int key = c >> 2, d0 = (c & 3) << 3;
    union { u32x4 v; unsigned short s[8]; } tmp;
    tmp.v = (key < NWIN) ? *(const u32x4*)(vp + (size_t)key * QKV_N + d0) : zv;
#pragma unroll
    for (int jj = 0; jj < 8; ++jj) vt[(d0 + jj) * 66 + key] = tmp.s[jj];
  }

  const f32x4 fz = {0.f, 0.f, 0.f, 0.f};
  f32x4 s[4][4];  // [mi = j-frag][ni = i-frag]
#pragma unroll
  for (int mi = 0; mi < 4; ++mi)
#pragma unroll
    for (int ni = 0; ni < 4; ++ni) s[mi][ni] = fz;
#pragma unroll
  for (int mi = 0; mi < 4; ++mi)
#pragma unroll
    for (int ni = 0; ni < 4; ++ni)
      s[mi][ni] = __builtin_amdgcn_mfma_f32_16x16x32_bf16(kf[mi], qf[ni], s[mi][ni], 0, 0, 0);

  union VU { unsigned int u[4]; bf16x8 v; };
  VU vfr[2][2];  // [nj][ks]
#pragma unroll
  for (int nj = 0; nj < 2; ++nj)
#pragma unroll
    for (int ks = 0; ks < 2; ++ks) {
      const int base = ((16 * nj + lr) * 66 + 32 * ks + 8 * lg) >> 1;
#pragma unroll
      for (int u = 0; u < 4; ++u) vfr[nj][ks].u[u] = ((const unsigned int*)vt)[base + u];
    }

  const float scale = 0.1767766952966369f;  // 32^-0.5
  const float* tbl = bmt + ((size_t)(w * NH + h) << 12);

  f32x4 o[4][2];
#pragma unroll
  for (int qi = 0; qi < 4; ++qi)
#pragma unroll
    for (int nj = 0; nj < 2; ++nj) o[qi][nj] = fz;

#pragma unroll
  for (int ni = 0; ni < 4; ++ni) {
    float v[16];
    float mx = -3e38f;
#pragma unroll
    for (int mi = 0; mi < 4; ++mi) {
      const f32x4 t4 = *(const f32x4*)(tbl + (16 * ni + lr) * 64 + 16 * mi + 4 * lg);
#pragma unroll
      for (int r = 0; r < 4; ++r) {
        v[mi * 4 + r] = fmaf(s[mi][ni][r], scale, t4[r]);
        mx = fmaxf(mx, v[mi * 4 + r]);
      }
    }
    mx = fmaxf(mx, __shfl_xor(mx, 16));
    mx = fmaxf(mx, __shfl_xor(mx, 32));
    float sum = 0.f;
#pragma unroll
    for (int t = 0; t < 16; ++t) {
      v[t] = __expf(v[t] - mx);
      sum += v[t];
    }
    sum += __shfl_xor(sum, 16);
    sum += __shfl_xor(sum, 32);
    const float inv = __builtin_amdgcn_rcpf(sum);

    const int ip = 16 * (ni & 1) + lr;
#pragma unroll
    for (int mi = 0; mi < 4; ++mi) {
      const unsigned int lo = (unsigned int)f32_to_bf16(v[mi * 4 + 0] * inv) |
                              ((unsigned int)f32_to_bf16(v[mi * 4 + 1] * inv) << 16);
      const unsigned int hi = (unsigned int)f32_to_bf16(v[mi * 4 + 2] * inv) |
                              ((unsigned int)f32_to_bf16(v[mi * 4 + 3] * inv) << 16);
      const int byteoff = 32 * mi + 8 * lg;
      const int sw = byteoff ^ ((ip & 7) << 4);
      uint2 w2; w2.x = lo; w2.y = hi;
      *(uint2*)((char*)pl + ip * 128 + sw) = w2;
    }

    if (ni & 1) {
      asm volatile("s_waitcnt lgkmcnt(0)" ::: "memory");
      __builtin_amdgcn_sched_barrier(0);
      const int half = ni >> 1;
#pragma unroll
      for (int q2 = 0; q2 < 2; ++q2) {
        const int qi = half * 2 + q2;
        const int ipr = 16 * q2 + lr;
#pragma unroll
        for (int ks = 0; ks < 2; ++ks) {
          const int bo = 64 * ks + 16 * lg;
          const int swr = bo ^ ((ipr & 7) << 4);
          const bf16x8 pa = *(const bf16x8*)((const char*)pl + ipr * 128 + swr);
#pragma unroll
          for (int nj = 0; nj < 2; ++nj)
            o[qi][nj] = __builtin_amdgcn_mfma_f32_16x16x32_bf16(pa, vfr[nj][ks].v, o[qi][nj], 0, 0, 0);
        }
      }
    }
  }

  const size_t orow = (size_t)b * NWIN;
#pragma unroll
  for (int qi = 0; qi < 4; ++qi)
#pragma unroll
    for (int r = 0; r < 4; ++r) {
      const int i = 16 * qi + 4 * lg + r;
      if (i < NWIN) {
#pragma unroll
        for (int nj = 0; nj < 2; ++nj)
          aout[(orow + i) * C_DIM + h * HD + 16 * nj + lr] = f32_to_bf16(o[qi][nj][r]);
      }
    }
}

// ---------------------------------------------------------------- launch
static const size_t SZ_QKV = (size_t)M_ROWS * QKV_N * 2;
static const size_t SZ_XB  = (size_t)M_ROWS * C_DIM * 2;
static const size_t SZ_WQ  = (size_t)QKV_N * C_DIM * 2;
static const size_t OFF_QKV = 0;
static const size_t OFF_XB  = OFF_QKV + SZ_QKV;   // x_bf16, later reused as attn_out
static const size_t OFF_WQ  = OFF_XB + SZ_XB;
static const size_t OFF_WP  = OFF_WQ + SZ_WQ;

extern "C" void kernel_launch(void* const* d_in, const int* in_sizes, int n_in,
                              void* d_out, int out_size, void* d_ws, size_t ws_size,
                              hipStream_t stream) {
  const float* x      = (const float*)d_in[0];
  const float* mask   = (const float*)d_in[1];
  const float* qkv_w  = (const float*)d_in[2];
  const float* qkv_b  = (const float*)d_in[3];
  const float* proj_w = (const float*)d_in[4];
  const float* proj_b = (const float*)d_in[5];
  const float* rel    = (const float*)d_in[6];
  float* out = (float*)d_out;

  char* ws = (char*)d_ws;
  unsigned short* qkvb = (unsigned short*)(ws + OFF_QKV);
  unsigned short* xb   = (unsigned short*)(ws + OFF_XB);
  unsigned short* wqT  = (unsigned short*)(ws + OFF_WQ);
  unsigned short* wpT  = (unsigned short*)(ws + OFF_WP);
  // bmt (16.78 MB) in d_out scratch: fully consumed by k_attn before final GEMM.
  float* bmt = (float*)d_out;

  k_cvt<<<2048, 256, 0, stream>>>(x, xb, M_ROWS * C_DIM / 4);
  k_transpose_cvt<<<dim3(QKV_N / 32, C_DIM / 32), 256, 0, stream>>>(qkv_w, wqT, C_DIM, QKV_N);
  k_transpose_cvt<<<dim3(C_DIM / 32, C_DIM / 32), 256, 0, stream>>>(proj_w, wpT, C_DIM, C_DIM);
  k_bm<<<(NMASK * NH * 64 * 64) / 256, 256, 0, stream>>>(mask, rel, bmt);

  // qkv = x @ qkv_w + qkv_b   (bf16 out), grid 6*392 = 2352 (%8==0)
  k_gemm256<1><<<(QKV_N / 256) * (M_ROWS / 256), 512, 0, stream>>>(
      xb, wqT, qkv_b, qkvb, M_ROWS, QKV_N, C_DIM);

  // attention -> attn_out (reuses xb region)
  k_attn<<<2048 * NH / 4, 256, 0, stream>>>(qkvb, bmt, xb);

  // out = attn_out @ proj_w + proj_b  (f32 out), grid 2*392 = 784 (%8==0)
  k_gemm256<0><<<(C_DIM / 256) * (M_ROWS / 256), 512, 0, stream>>>(
      xb, wpT, proj_b, out, M_ROWS, C_DIM, C_DIM);
}